// Round 5
// baseline (367.010 us; speedup 1.0000x reference)
//
#include <hip/hip_runtime.h>

#define NN 100000
#define EE 1600000
#define ELN 200000

#define NB 98           // dst buckets: dst >> 10, max 97
#define BKT_SHIFT 10
#define BKT_NODES 1024
#define MSB 256         // multisplit blocks
#define EPB (EE / MSB)  // 6250 edges per block

typedef __attribute__((ext_vector_type(4))) float f32x4;
typedef __attribute__((ext_vector_type(8))) short short8;

__device__ __forceinline__ unsigned short f2bf(float f) {
    unsigned u = __builtin_bit_cast(unsigned, f);
    u += 0x7FFF + ((u >> 16) & 1);   // round-to-nearest-even
    return (unsigned short)(u >> 16);
}
__device__ __forceinline__ float bf2f(unsigned short h) {
    return __builtin_bit_cast(float, (unsigned)h << 16);
}

// ----------------- weight pre-transpose: W[k][128] f32 -> WT[n][K] bf16 -----------------
__device__ __forceinline__ void convw_one(const float* __restrict__ W,
                                          unsigned short* __restrict__ WT, int K, int u) {
    int n = u & 127, kq = u >> 7;
    short8 t;
#pragma unroll
    for (int j = 0; j < 8; j++)
        t[j] = (short)f2bf(W[(size_t)(kq * 8 + j) * 128 + n]);
    *(short8*)(WT + (size_t)n * K + kq * 8) = t;
}

__global__ __launch_bounds__(256) void convw_kernel(const float* __restrict__ W1,
                                                    const float* __restrict__ W2,
                                                    const float* __restrict__ Wp1,
                                                    unsigned short* __restrict__ W1T,
                                                    unsigned short* __restrict__ W2T,
                                                    unsigned short* __restrict__ WpT) {
    int u = blockIdx.x * 256 + threadIdx.x;  // 8192 threads
    if (u < 2048) convw_one(W1, W1T, 128, u);
    else if (u < 4096) convw_one(W2, W2T, 128, u - 2048);
    else convw_one(Wp1, WpT, 256, u - 4096);
}

// ----------------- multisplit CSR build -----------------
__global__ __launch_bounds__(256) void ms_hist_kernel(const int* __restrict__ dst,
                                                      int* __restrict__ histM) {
    __shared__ int cnt[NB];
    int tid = threadIdx.x;
    if (tid < NB) cnt[tid] = 0;
    __syncthreads();
    int base = blockIdx.x * EPB;
    for (int i = tid; i < EPB; i += 256)
        atomicAdd(&cnt[dst[base + i] >> BKT_SHIFT], 1);
    __syncthreads();
    if (tid < NB) histM[tid * MSB + blockIdx.x] = cnt[tid];
}

// one-pass scan: 256 threads x 98 contiguous elements each (25088 total)
__global__ __launch_bounds__(256) void ms_scan_kernel(int* __restrict__ histM,
                                                      int* __restrict__ rowptr) {
    __shared__ int sm[256];
    int tid = threadIdx.x;
    const int CPT = NB * MSB / 256;  // 98
    int base = tid * CPT;
    int s = 0;
    for (int i = 0; i < CPT; i++) s += histM[base + i];
    sm[tid] = s;
    __syncthreads();
    for (int off = 1; off < 256; off <<= 1) {
        int add = (tid >= off) ? sm[tid - off] : 0;
        __syncthreads();
        sm[tid] += add;
        __syncthreads();
    }
    int run = sm[tid] - s;  // exclusive prefix of this thread's run
    for (int i = 0; i < CPT; i++) {
        int v = histM[base + i];
        histM[base + i] = run;
        run += v;
    }
    if (tid == 0) rowptr[NN] = EE;
}

__global__ __launch_bounds__(256) void ms_scatter_kernel(const int* __restrict__ src,
                                                         const int* __restrict__ dst,
                                                         const int* __restrict__ histO,
                                                         unsigned* __restrict__ tmp) {
    __shared__ int off[NB];
    int tid = threadIdx.x;
    if (tid < NB) off[tid] = histO[tid * MSB + blockIdx.x];
    __syncthreads();
    int base = blockIdx.x * EPB;
    for (int i = tid; i < EPB; i += 256) {
        int d = dst[base + i];
        int s = src[base + i];
        int b = d >> BKT_SHIFT;
        int pos = atomicAdd(&off[b], 1);
        tmp[pos] = ((unsigned)(d & (BKT_NODES - 1)) << 17) | (unsigned)s;
    }
}

// one block per bucket: build per-node counts, emit rowptr+dinv, scatter csr locally
__global__ __launch_bounds__(256) void bucket_csr_kernel(const unsigned* __restrict__ tmp,
                                                         const int* __restrict__ histO,
                                                         int* __restrict__ rowptr,
                                                         float* __restrict__ dinv,
                                                         int* __restrict__ csr) {
    __shared__ int cnt[BKT_NODES];
    __shared__ int lp[BKT_NODES];
    __shared__ int sm[256];
    int b = blockIdx.x;
    int tid = threadIdx.x;
    int gbase = histO[b * MSB];
    int gend = (b == NB - 1) ? EE : histO[(b + 1) * MSB];
    for (int i = tid; i < BKT_NODES; i += 256) cnt[i] = 0;
    __syncthreads();
    for (int i = gbase + tid; i < gend; i += 256)
        atomicAdd(&cnt[tmp[i] >> 17], 1);
    __syncthreads();
    // exclusive scan of cnt[1024] with 256 threads (4 elems each)
    int s0 = cnt[tid * 4], s1 = cnt[tid * 4 + 1], s2 = cnt[tid * 4 + 2], s3 = cnt[tid * 4 + 3];
    int tot = s0 + s1 + s2 + s3;
    sm[tid] = tot;
    __syncthreads();
    for (int off = 1; off < 256; off <<= 1) {
        int add = (tid >= off) ? sm[tid - off] : 0;
        __syncthreads();
        sm[tid] += add;
        __syncthreads();
    }
    int excl = sm[tid] - tot;
    lp[tid * 4] = excl;
    lp[tid * 4 + 1] = excl + s0;
    lp[tid * 4 + 2] = excl + s0 + s1;
    lp[tid * 4 + 3] = excl + s0 + s1 + s2;
    // emit rowptr + dinv, then reset cnt for position allocation
    int n0 = b << BKT_SHIFT;
#pragma unroll
    for (int q = 0; q < 4; q++) {
        int i = tid * 4 + q;
        int node = n0 + i;
        if (node < NN) {
            rowptr[node] = gbase + (q == 0 ? excl : lp[i]);
            int c = (q == 0) ? s0 : (q == 1 ? s1 : (q == 2 ? s2 : s3));
            dinv[node] = rsqrtf((float)c + 1.0f);
        }
    }
    cnt[tid * 4] = 0; cnt[tid * 4 + 1] = 0; cnt[tid * 4 + 2] = 0; cnt[tid * 4 + 3] = 0;
    __syncthreads();
    for (int i = gbase + tid; i < gend; i += 256) {
        unsigned p = tmp[i];
        int dl = p >> 17;
        int s = p & 0x1FFFF;
        int pos = atomicAdd(&cnt[dl], 1);
        csr[gbase + lp[dl] + pos] = s;
    }
}

// ----------------- GEMM via MFMA: out_bf16[N,128] = A[N,128] @ W[128,128] -----------------
// WT: pre-transposed bf16 [n][k]. Vector-staged into swizzled LDS.
template <bool A_IS_F32>
__global__ __launch_bounds__(256, 4) void gemm_mfma_kernel(const void* __restrict__ Av,
                                                           const unsigned short* __restrict__ WT,
                                                           unsigned short* __restrict__ out,
                                                           int nrows, int nchunks) {
    __shared__ __align__(16) char Wl[128 * 128 * 2];  // 32 KB: WT[n][k] bf16, swizzled
    int tid = threadIdx.x;
#pragma unroll
    for (int j = 0; j < 8; j++) {
        int slot = tid + j * 256;           // 2048 slots of 16B
        int n = slot >> 4, k0 = (slot & 15) * 8;
        int byte = (n * 256 + k0 * 2) ^ ((n & 7) << 4);
        *(short8*)(Wl + byte) = ((const short8*)WT)[slot];
    }
    __syncthreads();
    int wid = tid >> 6, l = tid & 63;
    int lhi = l >> 4, llo = l & 15;
    for (int chunk = blockIdx.x; chunk < nchunks; chunk += gridDim.x) {
        int r0 = chunk * 64 + wid * 16;
        int arow = r0 + llo;
        f32x4 acc[8];
#pragma unroll
        for (int c = 0; c < 8; c++) acc[c] = (f32x4)0.0f;
#pragma unroll
        for (int ks = 0; ks < 4; ks++) {
            int koff = ks * 32 + lhi * 8;
            short8 a;
            if (arow < nrows) {
                if (A_IS_F32) {
                    const float* ap = (const float*)Av + (size_t)arow * 128 + koff;
                    float4 v0 = *(const float4*)ap;
                    float4 v1 = *(const float4*)(ap + 4);
                    a[0] = (short)f2bf(v0.x); a[1] = (short)f2bf(v0.y);
                    a[2] = (short)f2bf(v0.z); a[3] = (short)f2bf(v0.w);
                    a[4] = (short)f2bf(v1.x); a[5] = (short)f2bf(v1.y);
                    a[6] = (short)f2bf(v1.z); a[7] = (short)f2bf(v1.w);
                } else {
                    a = *(const short8*)((const unsigned short*)Av + (size_t)arow * 128 + koff);
                }
            } else {
                a = (short8)(short)0;
            }
#pragma unroll
            for (int c = 0; c < 8; c++) {
                int n = c * 16 + llo;
                int byte = (n * 256 + koff * 2) ^ ((n & 7) << 4);
                short8 bfr = *(const short8*)(Wl + byte);
                acc[c] = __builtin_amdgcn_mfma_f32_16x16x32_bf16(a, bfr, acc[c], 0, 0, 0);
            }
        }
#pragma unroll
        for (int c = 0; c < 8; c++) {
            int col = c * 16 + llo;
#pragma unroll
            for (int j = 0; j < 4; j++) {
                int row = r0 + lhi * 4 + j;
                if (row < nrows) out[(size_t)row * 128 + col] = f2bf(acc[c][j]);
            }
        }
    }
}

// ----------------- aggregation: one wave per node, bf16 gather, fp32 acc ---------------
__global__ __launch_bounds__(256) void agg_bf16_kernel(const unsigned short* __restrict__ h,
                                                       const int* __restrict__ rowptr,
                                                       const int* __restrict__ csr,
                                                       const float* __restrict__ dinv,
                                                       const float* __restrict__ bias,
                                                       unsigned short* __restrict__ out,
                                                       int relu) {
    int wid = threadIdx.x >> 6, l = threadIdx.x & 63;
    int node = blockIdx.x * 4 + wid;
    if (node >= NN) return;
    const unsigned* hp = (const unsigned*)h;  // one dword = 2 bf16 features
    float dn = dinv[node];
    unsigned sv = hp[(size_t)node * 64 + l];
    float a0 = bf2f((unsigned short)sv) * dn * dn;
    float a1 = bf2f((unsigned short)(sv >> 16)) * dn * dn;
    int beg = rowptr[node], end = rowptr[node + 1];
    int i = beg;
    for (; i + 4 <= end; i += 4) {
        int s0 = csr[i], s1 = csr[i + 1], s2 = csr[i + 2], s3 = csr[i + 3];
        unsigned v0 = hp[(size_t)s0 * 64 + l];
        unsigned v1 = hp[(size_t)s1 * 64 + l];
        unsigned v2 = hp[(size_t)s2 * 64 + l];
        unsigned v3 = hp[(size_t)s3 * 64 + l];
        float c0 = dinv[s0] * dn, c1 = dinv[s1] * dn;
        float c2 = dinv[s2] * dn, c3 = dinv[s3] * dn;
        a0 += c0 * bf2f((unsigned short)v0); a1 += c0 * bf2f((unsigned short)(v0 >> 16));
        a0 += c1 * bf2f((unsigned short)v1); a1 += c1 * bf2f((unsigned short)(v1 >> 16));
        a0 += c2 * bf2f((unsigned short)v2); a1 += c2 * bf2f((unsigned short)(v2 >> 16));
        a0 += c3 * bf2f((unsigned short)v3); a1 += c3 * bf2f((unsigned short)(v3 >> 16));
    }
    for (; i < end; i++) {
        int s = csr[i];
        unsigned v = hp[(size_t)s * 64 + l];
        float c = dinv[s] * dn;
        a0 += c * bf2f((unsigned short)v);
        a1 += c * bf2f((unsigned short)(v >> 16));
    }
    a0 += bias[l * 2];
    a1 += bias[l * 2 + 1];
    if (relu) { a0 = fmaxf(a0, 0.f); a1 = fmaxf(a1, 0.f); }
    ((unsigned*)out)[(size_t)node * 64 + l] = (unsigned)f2bf(a0) | ((unsigned)f2bf(a1) << 16);
}

// ----------------- link scoring via MFMA -----------------
// 8 waves x 16 edges per block-iter; WpT pre-transposed bf16, vector-staged to LDS.
__global__ __launch_bounds__(512, 4) void link_mfma_kernel(const unsigned short* __restrict__ h,
                                                           const int* __restrict__ eli,
                                                           const unsigned short* __restrict__ WpT,
                                                           const float* __restrict__ bp1,
                                                           const float* __restrict__ Wp2,
                                                           const float* __restrict__ bp2,
                                                           float* __restrict__ out) {
    __shared__ __align__(16) char Wl[128 * 256 * 2];  // 64 KB: WpT[n][k] bf16, swizzled
    int tid = threadIdx.x;
#pragma unroll
    for (int j = 0; j < 8; j++) {
        int slot = tid + j * 512;           // 4096 slots of 16B
        int n = slot >> 5, k0 = (slot & 31) * 8;
        int byte = (n * 512 + k0 * 2) ^ ((n & 7) << 4);
        *(short8*)(Wl + byte) = ((const short8*)WpT)[slot];
    }
    __syncthreads();
    int wid = tid >> 6, l = tid & 63;
    int lhi = l >> 4, llo = l & 15;
    float b2 = bp2[0];
    const int NG = (ELN + 127) / 128;  // 1563, last group partial
    for (int g = blockIdx.x; g < NG; g += gridDim.x) {
        int e_base = g * 128 + wid * 16;
        if (e_base >= ELN) continue;
        int ea = e_base + llo;
        int es = eli[ea], et = eli[ELN + ea];
        f32x4 acc[8];
#pragma unroll
        for (int c = 0; c < 8; c++) acc[c] = (f32x4)0.0f;
#pragma unroll
        for (int ks = 0; ks < 8; ks++) {
            int kg = ks * 32 + lhi * 8;          // emb k in [0,256)
            int row = (kg < 128) ? es : et;
            int koff = kg & 127;
            short8 a = *(const short8*)(h + (size_t)row * 128 + koff);
#pragma unroll
            for (int c = 0; c < 8; c++) {
                int n = c * 16 + llo;
                int byte = (n * 512 + kg * 2) ^ ((n & 7) << 4);
                short8 bfr = *(const short8*)(Wl + byte);
                acc[c] = __builtin_amdgcn_mfma_f32_16x16x32_bf16(a, bfr, acc[c], 0, 0, 0);
            }
        }
        float p0 = 0.f, p1 = 0.f, p2 = 0.f, p3 = 0.f;
#pragma unroll
        for (int c = 0; c < 8; c++) {
            int col = c * 16 + llo;
            float bb = bp1[col];
            float w2 = Wp2[col];
            p0 += fmaxf(acc[c][0] + bb, 0.f) * w2;
            p1 += fmaxf(acc[c][1] + bb, 0.f) * w2;
            p2 += fmaxf(acc[c][2] + bb, 0.f) * w2;
            p3 += fmaxf(acc[c][3] + bb, 0.f) * w2;
        }
#pragma unroll
        for (int off = 1; off < 16; off <<= 1) {
            p0 += __shfl_xor(p0, off);
            p1 += __shfl_xor(p1, off);
            p2 += __shfl_xor(p2, off);
            p3 += __shfl_xor(p3, off);
        }
        if (llo == 0) {
            int e = e_base + lhi * 4;
            out[e + 0] = p0 + b2;
            out[e + 1] = p1 + b2;
            out[e + 2] = p2 + b2;
            out[e + 3] = p3 + b2;
        }
    }
}

extern "C" void kernel_launch(void* const* d_in, const int* in_sizes, int n_in,
                              void* d_out, int out_size, void* d_ws, size_t ws_size,
                              hipStream_t stream) {
    const float* x   = (const float*)d_in[0];
    const int*   ei  = (const int*)d_in[1];
    const int*   eli = (const int*)d_in[2];
    const float* W1  = (const float*)d_in[3];
    const float* b1  = (const float*)d_in[4];
    const float* W2  = (const float*)d_in[5];
    const float* b2  = (const float*)d_in[6];
    const float* Wp1 = (const float*)d_in[7];
    const float* bp1 = (const float*)d_in[8];
    const float* Wp2 = (const float*)d_in[9];
    const float* bp2 = (const float*)d_in[10];
    float* out = (float*)d_out;

    char* w = (char*)d_ws;
    auto alloc = [&](size_t bytes) {
        char* p = w;
        w += (bytes + 255) & ~(size_t)255;
        return p;
    };
    float*          dinv   = (float*)alloc((size_t)NN * 4);
    int*            rowptr = (int*)alloc((size_t)(NN + 1) * 4);
    int*            histM  = (int*)alloc((size_t)NB * MSB * 4);
    unsigned*       tmp    = (unsigned*)alloc((size_t)EE * 4);
    int*            csr    = (int*)alloc((size_t)EE * 4);
    unsigned short* hA     = (unsigned short*)alloc((size_t)NN * 128 * 2);
    unsigned short* hB     = (unsigned short*)alloc((size_t)NN * 128 * 2);
    unsigned short* W1T    = (unsigned short*)alloc((size_t)128 * 128 * 2);
    unsigned short* W2T    = (unsigned short*)alloc((size_t)128 * 128 * 2);
    unsigned short* WpT    = (unsigned short*)alloc((size_t)128 * 256 * 2);

    const int* srcv = ei;       // row 0
    const int* dstv = ei + EE;  // row 1

    // weight pre-transpose (bf16 [n][k])
    convw_kernel<<<32, 256, 0, stream>>>(W1, W2, Wp1, W1T, W2T, WpT);

    // CSR build: multisplit by dst bucket, then per-bucket local CSR (+rowptr,+dinv)
    ms_hist_kernel<<<MSB, 256, 0, stream>>>(dstv, histM);
    ms_scan_kernel<<<1, 256, 0, stream>>>(histM, rowptr);
    ms_scatter_kernel<<<MSB, 256, 0, stream>>>(srcv, dstv, histM, tmp);
    bucket_csr_kernel<<<NB, 256, 0, stream>>>(tmp, histM, rowptr, dinv, csr);

    int nchunks = (NN + 63) / 64;  // 1563
    // layer 1: hA = bf16(x @ W1); hB = bf16(relu(agg(hA) + b1))
    gemm_mfma_kernel<true><<<1024, 256, 0, stream>>>(x, W1T, hA, NN, nchunks);
    agg_bf16_kernel<<<NN / 4, 256, 0, stream>>>(hA, rowptr, csr, dinv, b1, hB, 1);
    // layer 2: hA = bf16(hB @ W2); hB = bf16(agg(hA) + b2)
    gemm_mfma_kernel<false><<<1024, 256, 0, stream>>>(hB, W2T, hA, NN, nchunks);
    agg_bf16_kernel<<<NN / 4, 256, 0, stream>>>(hA, rowptr, csr, dinv, b2, hB, 0);
    // link scoring
    link_mfma_kernel<<<512, 512, 0, stream>>>(hB, eli, WpT, bp1, Wp2, bp2, out);
}

// Round 6
// 330.343 us; speedup vs baseline: 1.1110x; 1.1110x over previous
//
#include <hip/hip_runtime.h>

#define NN 100000
#define EE 1600000
#define ELN 200000

#define NB 98           // dst buckets: dst >> 10, max 97
#define BKT_SHIFT 10
#define BKT_NODES 1024
#define MSB 256         // multisplit blocks
#define EPB (EE / MSB)  // 6250 edges per block

typedef __attribute__((ext_vector_type(4))) float f32x4;
typedef __attribute__((ext_vector_type(8))) short short8;

__device__ __forceinline__ unsigned short f2bf(float f) {
    unsigned u = __builtin_bit_cast(unsigned, f);
    u += 0x7FFF + ((u >> 16) & 1);   // round-to-nearest-even
    return (unsigned short)(u >> 16);
}
__device__ __forceinline__ float bf2f(unsigned short h) {
    return __builtin_bit_cast(float, (unsigned)h << 16);
}

// ----------------- weight pre-transpose: W[k][128] f32 -> WT[n][K] bf16 -----------------
__device__ __forceinline__ void convw_one(const float* __restrict__ W,
                                          unsigned short* __restrict__ WT, int K, int u) {
    int n = u & 127, kq = u >> 7;
    short8 t;
#pragma unroll
    for (int j = 0; j < 8; j++)
        t[j] = (short)f2bf(W[(size_t)(kq * 8 + j) * 128 + n]);
    *(short8*)(WT + (size_t)n * K + kq * 8) = t;
}

__global__ __launch_bounds__(256) void convw_kernel(const float* __restrict__ W1,
                                                    const float* __restrict__ W2,
                                                    const float* __restrict__ Wp1,
                                                    unsigned short* __restrict__ W1T,
                                                    unsigned short* __restrict__ W2T,
                                                    unsigned short* __restrict__ WpT) {
    int u = blockIdx.x * 256 + threadIdx.x;  // 8192 threads
    if (u < 2048) convw_one(W1, W1T, 128, u);
    else if (u < 4096) convw_one(W2, W2T, 128, u - 2048);
    else convw_one(Wp1, WpT, 256, u - 4096);
}

// ----------------- multisplit CSR build -----------------
__global__ __launch_bounds__(256) void ms_hist_kernel(const int* __restrict__ dst,
                                                      int* __restrict__ histM) {
    __shared__ int cnt[NB];
    int tid = threadIdx.x;
    if (tid < NB) cnt[tid] = 0;
    __syncthreads();
    int base = blockIdx.x * EPB;
    for (int i = tid; i < EPB; i += 256)
        atomicAdd(&cnt[dst[base + i] >> BKT_SHIFT], 1);
    __syncthreads();
    if (tid < NB) histM[tid * MSB + blockIdx.x] = cnt[tid];
}

// one-pass scan: 256 threads x 98 contiguous elements each (25088 total)
__global__ __launch_bounds__(256) void ms_scan_kernel(int* __restrict__ histM,
                                                      int* __restrict__ rowptr) {
    __shared__ int sm[256];
    int tid = threadIdx.x;
    const int CPT = NB * MSB / 256;  // 98
    int base = tid * CPT;
    int s = 0;
    for (int i = 0; i < CPT; i++) s += histM[base + i];
    sm[tid] = s;
    __syncthreads();
    for (int off = 1; off < 256; off <<= 1) {
        int add = (tid >= off) ? sm[tid - off] : 0;
        __syncthreads();
        sm[tid] += add;
        __syncthreads();
    }
    int run = sm[tid] - s;  // exclusive prefix of this thread's run
    for (int i = 0; i < CPT; i++) {
        int v = histM[base + i];
        histM[base + i] = run;
        run += v;
    }
    if (tid == 0) rowptr[NN] = EE;
}

__global__ __launch_bounds__(256) void ms_scatter_kernel(const int* __restrict__ src,
                                                         const int* __restrict__ dst,
                                                         const int* __restrict__ histO,
                                                         unsigned* __restrict__ tmp) {
    __shared__ int off[NB];
    int tid = threadIdx.x;
    if (tid < NB) off[tid] = histO[tid * MSB + blockIdx.x];
    __syncthreads();
    int base = blockIdx.x * EPB;
    for (int i = tid; i < EPB; i += 256) {
        int d = dst[base + i];
        int s = src[base + i];
        int b = d >> BKT_SHIFT;
        int pos = atomicAdd(&off[b], 1);
        tmp[pos] = ((unsigned)(d & (BKT_NODES - 1)) << 17) | (unsigned)s;
    }
}

// one block per bucket: build per-node counts, emit rowptr+dinv, scatter csr locally
__global__ __launch_bounds__(256) void bucket_csr_kernel(const unsigned* __restrict__ tmp,
                                                         const int* __restrict__ histO,
                                                         int* __restrict__ rowptr,
                                                         float* __restrict__ dinv,
                                                         int* __restrict__ csr) {
    __shared__ int cnt[BKT_NODES];
    __shared__ int lp[BKT_NODES];
    __shared__ int sm[256];
    int b = blockIdx.x;
    int tid = threadIdx.x;
    int gbase = histO[b * MSB];
    int gend = (b == NB - 1) ? EE : histO[(b + 1) * MSB];
    for (int i = tid; i < BKT_NODES; i += 256) cnt[i] = 0;
    __syncthreads();
    for (int i = gbase + tid; i < gend; i += 256)
        atomicAdd(&cnt[tmp[i] >> 17], 1);
    __syncthreads();
    // exclusive scan of cnt[1024] with 256 threads (4 elems each)
    int s0 = cnt[tid * 4], s1 = cnt[tid * 4 + 1], s2 = cnt[tid * 4 + 2], s3 = cnt[tid * 4 + 3];
    int tot = s0 + s1 + s2 + s3;
    sm[tid] = tot;
    __syncthreads();
    for (int off = 1; off < 256; off <<= 1) {
        int add = (tid >= off) ? sm[tid - off] : 0;
        __syncthreads();
        sm[tid] += add;
        __syncthreads();
    }
    int excl = sm[tid] - tot;
    lp[tid * 4] = excl;
    lp[tid * 4 + 1] = excl + s0;
    lp[tid * 4 + 2] = excl + s0 + s1;
    lp[tid * 4 + 3] = excl + s0 + s1 + s2;
    // emit rowptr + dinv, then reset cnt for position allocation
    int n0 = b << BKT_SHIFT;
#pragma unroll
    for (int q = 0; q < 4; q++) {
        int i = tid * 4 + q;
        int node = n0 + i;
        if (node < NN) {
            rowptr[node] = gbase + (q == 0 ? excl : lp[i]);
            int c = (q == 0) ? s0 : (q == 1 ? s1 : (q == 2 ? s2 : s3));
            dinv[node] = rsqrtf((float)c + 1.0f);
        }
    }
    cnt[tid * 4] = 0; cnt[tid * 4 + 1] = 0; cnt[tid * 4 + 2] = 0; cnt[tid * 4 + 3] = 0;
    __syncthreads();
    for (int i = gbase + tid; i < gend; i += 256) {
        unsigned p = tmp[i];
        int dl = p >> 17;
        int s = p & 0x1FFFF;
        int pos = atomicAdd(&cnt[dl], 1);
        csr[gbase + lp[dl] + pos] = s;
    }
}

// ----------------- GEMM via MFMA: out_bf16[N,128] = A[N,128] @ W[128,128] -----------------
// WT: pre-transposed bf16 [n][k]. Vector-staged into swizzled LDS.
template <bool A_IS_F32>
__global__ __launch_bounds__(256) void gemm_mfma_kernel(const void* __restrict__ Av,
                                                        const unsigned short* __restrict__ WT,
                                                        unsigned short* __restrict__ out,
                                                        int nrows, int nchunks) {
    __shared__ __align__(16) char Wl[128 * 128 * 2];  // 32 KB: WT[n][k] bf16, swizzled
    int tid = threadIdx.x;
#pragma unroll
    for (int j = 0; j < 8; j++) {
        int slot = tid + j * 256;           // 2048 slots of 16B
        int n = slot >> 4, k0 = (slot & 15) * 8;
        int byte = (n * 256 + k0 * 2) ^ ((n & 7) << 4);
        *(short8*)(Wl + byte) = ((const short8*)WT)[slot];
    }
    __syncthreads();
    int wid = tid >> 6, l = tid & 63;
    int lhi = l >> 4, llo = l & 15;
    for (int chunk = blockIdx.x; chunk < nchunks; chunk += gridDim.x) {
        int r0 = chunk * 64 + wid * 16;
        int arow = r0 + llo;
        f32x4 acc[8];
#pragma unroll
        for (int c = 0; c < 8; c++) acc[c] = (f32x4)0.0f;
#pragma unroll
        for (int ks = 0; ks < 4; ks++) {
            int koff = ks * 32 + lhi * 8;
            short8 a;
            if (arow < nrows) {
                if (A_IS_F32) {
                    const float* ap = (const float*)Av + (size_t)arow * 128 + koff;
                    float4 v0 = *(const float4*)ap;
                    float4 v1 = *(const float4*)(ap + 4);
                    a[0] = (short)f2bf(v0.x); a[1] = (short)f2bf(v0.y);
                    a[2] = (short)f2bf(v0.z); a[3] = (short)f2bf(v0.w);
                    a[4] = (short)f2bf(v1.x); a[5] = (short)f2bf(v1.y);
                    a[6] = (short)f2bf(v1.z); a[7] = (short)f2bf(v1.w);
                } else {
                    a = *(const short8*)((const unsigned short*)Av + (size_t)arow * 128 + koff);
                }
            } else {
                a = (short8)(short)0;
            }
#pragma unroll
            for (int c = 0; c < 8; c++) {
                int n = c * 16 + llo;
                int byte = (n * 256 + koff * 2) ^ ((n & 7) << 4);
                short8 bfr = *(const short8*)(Wl + byte);
                acc[c] = __builtin_amdgcn_mfma_f32_16x16x32_bf16(a, bfr, acc[c], 0, 0, 0);
            }
        }
#pragma unroll
        for (int c = 0; c < 8; c++) {
            int col = c * 16 + llo;
#pragma unroll
            for (int j = 0; j < 4; j++) {
                int row = r0 + lhi * 4 + j;
                if (row < nrows) out[(size_t)row * 128 + col] = f2bf(acc[c][j]);
            }
        }
    }
}

// ----------------- aggregation: one wave per node, bf16 gather, fp32 acc ---------------
// unroll-8 gather pipeline; csr streamed nontemporal; output stored nontemporal.
__global__ __launch_bounds__(256) void agg_bf16_kernel(const unsigned short* __restrict__ h,
                                                       const int* __restrict__ rowptr,
                                                       const int* __restrict__ csr,
                                                       const float* __restrict__ dinv,
                                                       const float* __restrict__ bias,
                                                       unsigned short* __restrict__ out,
                                                       int relu) {
    int wid = threadIdx.x >> 6, l = threadIdx.x & 63;
    int node = blockIdx.x * 4 + wid;
    if (node >= NN) return;
    const unsigned* hp = (const unsigned*)h;  // one dword = 2 bf16 features
    float dn = dinv[node];
    unsigned sv = hp[(size_t)node * 64 + l];
    float a0 = bf2f((unsigned short)sv) * dn * dn;
    float a1 = bf2f((unsigned short)(sv >> 16)) * dn * dn;
    int beg = rowptr[node], end = rowptr[node + 1];
    int i = beg;
    for (; i + 8 <= end; i += 8) {
        int s[8];
        unsigned v[8];
        float c[8];
#pragma unroll
        for (int j = 0; j < 8; j++) s[j] = __builtin_nontemporal_load(csr + i + j);
#pragma unroll
        for (int j = 0; j < 8; j++) v[j] = hp[(size_t)s[j] * 64 + l];
#pragma unroll
        for (int j = 0; j < 8; j++) c[j] = dinv[s[j]] * dn;
#pragma unroll
        for (int j = 0; j < 8; j++) {
            a0 += c[j] * bf2f((unsigned short)v[j]);
            a1 += c[j] * bf2f((unsigned short)(v[j] >> 16));
        }
    }
    for (; i < end; i++) {
        int s = __builtin_nontemporal_load(csr + i);
        unsigned v = hp[(size_t)s * 64 + l];
        float c = dinv[s] * dn;
        a0 += c * bf2f((unsigned short)v);
        a1 += c * bf2f((unsigned short)(v >> 16));
    }
    a0 += bias[l * 2];
    a1 += bias[l * 2 + 1];
    if (relu) { a0 = fmaxf(a0, 0.f); a1 = fmaxf(a1, 0.f); }
    unsigned packed = (unsigned)f2bf(a0) | ((unsigned)f2bf(a1) << 16);
    __builtin_nontemporal_store(packed, (unsigned*)out + (size_t)node * 64 + l);
}

// ----------------- link scoring via MFMA -----------------
// 8 waves x 16 edges per block-iter; WpT pre-transposed bf16, vector-staged to LDS.
__global__ __launch_bounds__(512, 2) void link_mfma_kernel(const unsigned short* __restrict__ h,
                                                           const int* __restrict__ eli,
                                                           const unsigned short* __restrict__ WpT,
                                                           const float* __restrict__ bp1,
                                                           const float* __restrict__ Wp2,
                                                           const float* __restrict__ bp2,
                                                           float* __restrict__ out) {
    __shared__ __align__(16) char Wl[128 * 256 * 2];  // 64 KB: WpT[n][k] bf16, swizzled
    int tid = threadIdx.x;
#pragma unroll
    for (int j = 0; j < 8; j++) {
        int slot = tid + j * 512;           // 4096 slots of 16B
        int n = slot >> 5, k0 = (slot & 31) * 8;
        int byte = (n * 512 + k0 * 2) ^ ((n & 7) << 4);
        *(short8*)(Wl + byte) = ((const short8*)WpT)[slot];
    }
    __syncthreads();
    int wid = tid >> 6, l = tid & 63;
    int lhi = l >> 4, llo = l & 15;
    float b2 = bp2[0];
    const int NG = (ELN + 127) / 128;  // 1563, last group partial
    for (int g = blockIdx.x; g < NG; g += gridDim.x) {
        int e_base = g * 128 + wid * 16;
        if (e_base >= ELN) continue;
        int ea = e_base + llo;
        int es = eli[ea], et = eli[ELN + ea];
        f32x4 acc[8];
#pragma unroll
        for (int c = 0; c < 8; c++) acc[c] = (f32x4)0.0f;
#pragma unroll
        for (int ks = 0; ks < 8; ks++) {
            int kg = ks * 32 + lhi * 8;          // emb k in [0,256)
            int row = (kg < 128) ? es : et;
            int koff = kg & 127;
            short8 a = *(const short8*)(h + (size_t)row * 128 + koff);
#pragma unroll
            for (int c = 0; c < 8; c++) {
                int n = c * 16 + llo;
                int byte = (n * 512 + kg * 2) ^ ((n & 7) << 4);
                short8 bfr = *(const short8*)(Wl + byte);
                acc[c] = __builtin_amdgcn_mfma_f32_16x16x32_bf16(a, bfr, acc[c], 0, 0, 0);
            }
        }
        float p0 = 0.f, p1 = 0.f, p2 = 0.f, p3 = 0.f;
#pragma unroll
        for (int c = 0; c < 8; c++) {
            int col = c * 16 + llo;
            float bb = bp1[col];
            float w2 = Wp2[col];
            p0 += fmaxf(acc[c][0] + bb, 0.f) * w2;
            p1 += fmaxf(acc[c][1] + bb, 0.f) * w2;
            p2 += fmaxf(acc[c][2] + bb, 0.f) * w2;
            p3 += fmaxf(acc[c][3] + bb, 0.f) * w2;
        }
#pragma unroll
        for (int off = 1; off < 16; off <<= 1) {
            p0 += __shfl_xor(p0, off);
            p1 += __shfl_xor(p1, off);
            p2 += __shfl_xor(p2, off);
            p3 += __shfl_xor(p3, off);
        }
        if (llo == 0) {
            int e = e_base + lhi * 4;
            out[e + 0] = p0 + b2;
            out[e + 1] = p1 + b2;
            out[e + 2] = p2 + b2;
            out[e + 3] = p3 + b2;
        }
    }
}

extern "C" void kernel_launch(void* const* d_in, const int* in_sizes, int n_in,
                              void* d_out, int out_size, void* d_ws, size_t ws_size,
                              hipStream_t stream) {
    const float* x   = (const float*)d_in[0];
    const int*   ei  = (const int*)d_in[1];
    const int*   eli = (const int*)d_in[2];
    const float* W1  = (const float*)d_in[3];
    const float* b1  = (const float*)d_in[4];
    const float* W2  = (const float*)d_in[5];
    const float* b2  = (const float*)d_in[6];
    const float* Wp1 = (const float*)d_in[7];
    const float* bp1 = (const float*)d_in[8];
    const float* Wp2 = (const float*)d_in[9];
    const float* bp2 = (const float*)d_in[10];
    float* out = (float*)d_out;

    char* w = (char*)d_ws;
    auto alloc = [&](size_t bytes) {
        char* p = w;
        w += (bytes + 255) & ~(size_t)255;
        return p;
    };
    float*          dinv   = (float*)alloc((size_t)NN * 4);
    int*            rowptr = (int*)alloc((size_t)(NN + 1) * 4);
    int*            histM  = (int*)alloc((size_t)NB * MSB * 4);
    unsigned*       tmp    = (unsigned*)alloc((size_t)EE * 4);
    int*            csr    = (int*)alloc((size_t)EE * 4);
    unsigned short* hA     = (unsigned short*)alloc((size_t)NN * 128 * 2);
    unsigned short* hB     = (unsigned short*)alloc((size_t)NN * 128 * 2);
    unsigned short* W1T    = (unsigned short*)alloc((size_t)128 * 128 * 2);
    unsigned short* W2T    = (unsigned short*)alloc((size_t)128 * 128 * 2);
    unsigned short* WpT    = (unsigned short*)alloc((size_t)128 * 256 * 2);

    const int* srcv = ei;       // row 0
    const int* dstv = ei + EE;  // row 1

    // weight pre-transpose (bf16 [n][k])
    convw_kernel<<<32, 256, 0, stream>>>(W1, W2, Wp1, W1T, W2T, WpT);

    // CSR build: multisplit by dst bucket, then per-bucket local CSR (+rowptr,+dinv)
    ms_hist_kernel<<<MSB, 256, 0, stream>>>(dstv, histM);
    ms_scan_kernel<<<1, 256, 0, stream>>>(histM, rowptr);
    ms_scatter_kernel<<<MSB, 256, 0, stream>>>(srcv, dstv, histM, tmp);
    bucket_csr_kernel<<<NB, 256, 0, stream>>>(tmp, histM, rowptr, dinv, csr);

    int nchunks = (NN + 63) / 64;  // 1563
    // layer 1: hA = bf16(x @ W1); hB = bf16(relu(agg(hA) + b1))
    gemm_mfma_kernel<true><<<1024, 256, 0, stream>>>(x, W1T, hA, NN, nchunks);
    agg_bf16_kernel<<<NN / 4, 256, 0, stream>>>(hA, rowptr, csr, dinv, b1, hB, 1);
    // layer 2: hA = bf16(hB @ W2); hB = bf16(agg(hA) + b2)
    gemm_mfma_kernel<false><<<1024, 256, 0, stream>>>(hB, W2T, hA, NN, nchunks);
    agg_bf16_kernel<<<NN / 4, 256, 0, stream>>>(hA, rowptr, csr, dinv, b2, hB, 0);
    // link scoring
    link_mfma_kernel<<<512, 512, 0, stream>>>(hB, eli, WpT, bp1, Wp2, bp2, out);
}

// Round 7
// 290.895 us; speedup vs baseline: 1.2617x; 1.1356x over previous
//
#include <hip/hip_runtime.h>

#define NN 100000
#define EE 1600000
#define ELN 200000

#define NB 98           // dst buckets: dst >> 10, max 97
#define BKT_SHIFT 10
#define BKT_NODES 1024
#define MSB 256         // multisplit blocks
#define EPB (EE / MSB)  // 6250 edges per block

typedef __attribute__((ext_vector_type(4))) float f32x4;
typedef __attribute__((ext_vector_type(8))) short short8;

__device__ __forceinline__ unsigned short f2bf(float f) {
    unsigned u = __builtin_bit_cast(unsigned, f);
    u += 0x7FFF + ((u >> 16) & 1);   // round-to-nearest-even
    return (unsigned short)(u >> 16);
}
__device__ __forceinline__ float bf2f(unsigned short h) {
    return __builtin_bit_cast(float, (unsigned)h << 16);
}

// ----------------- weight pre-transpose: W[k][128] f32 -> WT[n][K] bf16 -----------------
__device__ __forceinline__ void convw_one(const float* __restrict__ W,
                                          unsigned short* __restrict__ WT, int K, int u) {
    int n = u & 127, kq = u >> 7;
    short8 t;
#pragma unroll
    for (int j = 0; j < 8; j++)
        t[j] = (short)f2bf(W[(size_t)(kq * 8 + j) * 128 + n]);
    *(short8*)(WT + (size_t)n * K + kq * 8) = t;
}

__global__ __launch_bounds__(256) void convw_kernel(const float* __restrict__ W1,
                                                    const float* __restrict__ W2,
                                                    const float* __restrict__ Wp1,
                                                    unsigned short* __restrict__ W1T,
                                                    unsigned short* __restrict__ W2T,
                                                    unsigned short* __restrict__ WpT) {
    int u = blockIdx.x * 256 + threadIdx.x;  // 8192 threads
    if (u < 2048) convw_one(W1, W1T, 128, u);
    else if (u < 4096) convw_one(W2, W2T, 128, u - 2048);
    else convw_one(Wp1, WpT, 256, u - 4096);
}

// ----------------- multisplit CSR build -----------------
__global__ __launch_bounds__(256) void ms_hist_kernel(const int* __restrict__ dst,
                                                      int* __restrict__ histM) {
    __shared__ int cnt[NB];
    int tid = threadIdx.x;
    if (tid < NB) cnt[tid] = 0;
    __syncthreads();
    int base = blockIdx.x * EPB;
    for (int i = tid; i < EPB; i += 256)
        atomicAdd(&cnt[dst[base + i] >> BKT_SHIFT], 1);
    __syncthreads();
    if (tid < NB) histM[tid * MSB + blockIdx.x] = cnt[tid];
}

// one-pass scan: 256 threads x 98 contiguous elements each (25088 total)
__global__ __launch_bounds__(256) void ms_scan_kernel(int* __restrict__ histM,
                                                      int* __restrict__ rowptr) {
    __shared__ int sm[256];
    int tid = threadIdx.x;
    const int CPT = NB * MSB / 256;  // 98
    int base = tid * CPT;
    int s = 0;
    for (int i = 0; i < CPT; i++) s += histM[base + i];
    sm[tid] = s;
    __syncthreads();
    for (int off = 1; off < 256; off <<= 1) {
        int add = (tid >= off) ? sm[tid - off] : 0;
        __syncthreads();
        sm[tid] += add;
        __syncthreads();
    }
    int run = sm[tid] - s;  // exclusive prefix of this thread's run
    for (int i = 0; i < CPT; i++) {
        int v = histM[base + i];
        histM[base + i] = run;
        run += v;
    }
    if (tid == 0) rowptr[NN] = EE;
}

__global__ __launch_bounds__(256) void ms_scatter_kernel(const int* __restrict__ src,
                                                         const int* __restrict__ dst,
                                                         const int* __restrict__ histO,
                                                         unsigned* __restrict__ tmp) {
    __shared__ int off[NB];
    int tid = threadIdx.x;
    if (tid < NB) off[tid] = histO[tid * MSB + blockIdx.x];
    __syncthreads();
    int base = blockIdx.x * EPB;
    for (int i = tid; i < EPB; i += 256) {
        int d = dst[base + i];
        int s = src[base + i];
        int b = d >> BKT_SHIFT;
        int pos = atomicAdd(&off[b], 1);
        tmp[pos] = ((unsigned)(d & (BKT_NODES - 1)) << 17) | (unsigned)s;
    }
}

// one block per bucket: build per-node counts, emit rowptr+dinv, scatter csr locally
__global__ __launch_bounds__(256) void bucket_csr_kernel(const unsigned* __restrict__ tmp,
                                                         const int* __restrict__ histO,
                                                         int* __restrict__ rowptr,
                                                         float* __restrict__ dinv,
                                                         int* __restrict__ csr) {
    __shared__ int cnt[BKT_NODES];
    __shared__ int lp[BKT_NODES];
    __shared__ int sm[256];
    int b = blockIdx.x;
    int tid = threadIdx.x;
    int gbase = histO[b * MSB];
    int gend = (b == NB - 1) ? EE : histO[(b + 1) * MSB];
    for (int i = tid; i < BKT_NODES; i += 256) cnt[i] = 0;
    __syncthreads();
    for (int i = gbase + tid; i < gend; i += 256)
        atomicAdd(&cnt[tmp[i] >> 17], 1);
    __syncthreads();
    // exclusive scan of cnt[1024] with 256 threads (4 elems each)
    int s0 = cnt[tid * 4], s1 = cnt[tid * 4 + 1], s2 = cnt[tid * 4 + 2], s3 = cnt[tid * 4 + 3];
    int tot = s0 + s1 + s2 + s3;
    sm[tid] = tot;
    __syncthreads();
    for (int off = 1; off < 256; off <<= 1) {
        int add = (tid >= off) ? sm[tid - off] : 0;
        __syncthreads();
        sm[tid] += add;
        __syncthreads();
    }
    int excl = sm[tid] - tot;
    lp[tid * 4] = excl;
    lp[tid * 4 + 1] = excl + s0;
    lp[tid * 4 + 2] = excl + s0 + s1;
    lp[tid * 4 + 3] = excl + s0 + s1 + s2;
    // emit rowptr + dinv, then reset cnt for position allocation
    int n0 = b << BKT_SHIFT;
#pragma unroll
    for (int q = 0; q < 4; q++) {
        int i = tid * 4 + q;
        int node = n0 + i;
        if (node < NN) {
            rowptr[node] = gbase + (q == 0 ? excl : lp[i]);
            int c = (q == 0) ? s0 : (q == 1 ? s1 : (q == 2 ? s2 : s3));
            dinv[node] = rsqrtf((float)c + 1.0f);
        }
    }
    cnt[tid * 4] = 0; cnt[tid * 4 + 1] = 0; cnt[tid * 4 + 2] = 0; cnt[tid * 4 + 3] = 0;
    __syncthreads();
    for (int i = gbase + tid; i < gend; i += 256) {
        unsigned p = tmp[i];
        int dl = p >> 17;
        int s = p & 0x1FFFF;
        int pos = atomicAdd(&cnt[dl], 1);
        csr[gbase + lp[dl] + pos] = s;
    }
}

// ----------------- GEMM via MFMA: out_bf16[N,128] = A[N,128] @ W[128,128] -----------------
// WT: pre-transposed bf16 [n][k]. Vector-staged into swizzled LDS.
template <bool A_IS_F32>
__global__ __launch_bounds__(256) void gemm_mfma_kernel(const void* __restrict__ Av,
                                                        const unsigned short* __restrict__ WT,
                                                        unsigned short* __restrict__ out,
                                                        int nrows, int nchunks) {
    __shared__ __align__(16) char Wl[128 * 128 * 2];  // 32 KB: WT[n][k] bf16, swizzled
    int tid = threadIdx.x;
#pragma unroll
    for (int j = 0; j < 8; j++) {
        int slot = tid + j * 256;           // 2048 slots of 16B
        int n = slot >> 4, k0 = (slot & 15) * 8;
        int byte = (n * 256 + k0 * 2) ^ ((n & 7) << 4);
        *(short8*)(Wl + byte) = ((const short8*)WT)[slot];
    }
    __syncthreads();
    int wid = tid >> 6, l = tid & 63;
    int lhi = l >> 4, llo = l & 15;
    for (int chunk = blockIdx.x; chunk < nchunks; chunk += gridDim.x) {
        int r0 = chunk * 64 + wid * 16;
        int arow = r0 + llo;
        f32x4 acc[8];
#pragma unroll
        for (int c = 0; c < 8; c++) acc[c] = (f32x4)0.0f;
#pragma unroll
        for (int ks = 0; ks < 4; ks++) {
            int koff = ks * 32 + lhi * 8;
            short8 a;
            if (arow < nrows) {
                if (A_IS_F32) {
                    const float* ap = (const float*)Av + (size_t)arow * 128 + koff;
                    float4 v0 = *(const float4*)ap;
                    float4 v1 = *(const float4*)(ap + 4);
                    a[0] = (short)f2bf(v0.x); a[1] = (short)f2bf(v0.y);
                    a[2] = (short)f2bf(v0.z); a[3] = (short)f2bf(v0.w);
                    a[4] = (short)f2bf(v1.x); a[5] = (short)f2bf(v1.y);
                    a[6] = (short)f2bf(v1.z); a[7] = (short)f2bf(v1.w);
                } else {
                    a = *(const short8*)((const unsigned short*)Av + (size_t)arow * 128 + koff);
                }
            } else {
                a = (short8)(short)0;
            }
#pragma unroll
            for (int c = 0; c < 8; c++) {
                int n = c * 16 + llo;
                int byte = (n * 256 + koff * 2) ^ ((n & 7) << 4);
                short8 bfr = *(const short8*)(Wl + byte);
                acc[c] = __builtin_amdgcn_mfma_f32_16x16x32_bf16(a, bfr, acc[c], 0, 0, 0);
            }
        }
#pragma unroll
        for (int c = 0; c < 8; c++) {
            int col = c * 16 + llo;
#pragma unroll
            for (int j = 0; j < 4; j++) {
                int row = r0 + lhi * 4 + j;
                if (row < nrows) out[(size_t)row * 128 + col] = f2bf(acc[c][j]);
            }
        }
    }
}

// ----------------- aggregation: one wave per node, bf16 gather, fp32 acc ---------------
// unroll-8 gather pipeline, plain (cached) loads everywhere.
__global__ __launch_bounds__(256) void agg_bf16_kernel(const unsigned short* __restrict__ h,
                                                       const int* __restrict__ rowptr,
                                                       const int* __restrict__ csr,
                                                       const float* __restrict__ dinv,
                                                       const float* __restrict__ bias,
                                                       unsigned short* __restrict__ out,
                                                       int relu) {
    int wid = threadIdx.x >> 6, l = threadIdx.x & 63;
    int node = blockIdx.x * 4 + wid;
    if (node >= NN) return;
    const unsigned* hp = (const unsigned*)h;  // one dword = 2 bf16 features
    float dn = dinv[node];
    unsigned sv = hp[(size_t)node * 64 + l];
    float a0 = bf2f((unsigned short)sv) * dn * dn;
    float a1 = bf2f((unsigned short)(sv >> 16)) * dn * dn;
    int beg = rowptr[node], end = rowptr[node + 1];
    int i = beg;
    for (; i + 8 <= end; i += 8) {
        int s[8];
        unsigned v[8];
        float c[8];
#pragma unroll
        for (int j = 0; j < 8; j++) s[j] = csr[i + j];
#pragma unroll
        for (int j = 0; j < 8; j++) v[j] = hp[(size_t)s[j] * 64 + l];
#pragma unroll
        for (int j = 0; j < 8; j++) c[j] = dinv[s[j]] * dn;
#pragma unroll
        for (int j = 0; j < 8; j++) {
            a0 += c[j] * bf2f((unsigned short)v[j]);
            a1 += c[j] * bf2f((unsigned short)(v[j] >> 16));
        }
    }
    for (; i < end; i++) {
        int s = csr[i];
        unsigned v = hp[(size_t)s * 64 + l];
        float c = dinv[s] * dn;
        a0 += c * bf2f((unsigned short)v);
        a1 += c * bf2f((unsigned short)(v >> 16));
    }
    a0 += bias[l * 2];
    a1 += bias[l * 2 + 1];
    if (relu) { a0 = fmaxf(a0, 0.f); a1 = fmaxf(a1, 0.f); }
    ((unsigned*)out)[(size_t)node * 64 + l] = (unsigned)f2bf(a0) | ((unsigned)f2bf(a1) << 16);
}

// ----------------- link scoring via MFMA -----------------
// 8 waves x 16 edges per block-iter; WpT pre-transposed bf16, vector-staged to LDS.
__global__ __launch_bounds__(512, 2) void link_mfma_kernel(const unsigned short* __restrict__ h,
                                                           const int* __restrict__ eli,
                                                           const unsigned short* __restrict__ WpT,
                                                           const float* __restrict__ bp1,
                                                           const float* __restrict__ Wp2,
                                                           const float* __restrict__ bp2,
                                                           float* __restrict__ out) {
    __shared__ __align__(16) char Wl[128 * 256 * 2];  // 64 KB: WpT[n][k] bf16, swizzled
    int tid = threadIdx.x;
#pragma unroll
    for (int j = 0; j < 8; j++) {
        int slot = tid + j * 512;           // 4096 slots of 16B
        int n = slot >> 5, k0 = (slot & 31) * 8;
        int byte = (n * 512 + k0 * 2) ^ ((n & 7) << 4);
        *(short8*)(Wl + byte) = ((const short8*)WpT)[slot];
    }
    __syncthreads();
    int wid = tid >> 6, l = tid & 63;
    int lhi = l >> 4, llo = l & 15;
    float b2 = bp2[0];
    const int NG = (ELN + 127) / 128;  // 1563, last group partial
    for (int g = blockIdx.x; g < NG; g += gridDim.x) {
        int e_base = g * 128 + wid * 16;
        if (e_base >= ELN) continue;
        int ea = e_base + llo;
        int es = eli[ea], et = eli[ELN + ea];
        f32x4 acc[8];
#pragma unroll
        for (int c = 0; c < 8; c++) acc[c] = (f32x4)0.0f;
#pragma unroll
        for (int ks = 0; ks < 8; ks++) {
            int kg = ks * 32 + lhi * 8;          // emb k in [0,256)
            int row = (kg < 128) ? es : et;
            int koff = kg & 127;
            short8 a = *(const short8*)(h + (size_t)row * 128 + koff);
#pragma unroll
            for (int c = 0; c < 8; c++) {
                int n = c * 16 + llo;
                int byte = (n * 512 + kg * 2) ^ ((n & 7) << 4);
                short8 bfr = *(const short8*)(Wl + byte);
                acc[c] = __builtin_amdgcn_mfma_f32_16x16x32_bf16(a, bfr, acc[c], 0, 0, 0);
            }
        }
        float p0 = 0.f, p1 = 0.f, p2 = 0.f, p3 = 0.f;
#pragma unroll
        for (int c = 0; c < 8; c++) {
            int col = c * 16 + llo;
            float bb = bp1[col];
            float w2 = Wp2[col];
            p0 += fmaxf(acc[c][0] + bb, 0.f) * w2;
            p1 += fmaxf(acc[c][1] + bb, 0.f) * w2;
            p2 += fmaxf(acc[c][2] + bb, 0.f) * w2;
            p3 += fmaxf(acc[c][3] + bb, 0.f) * w2;
        }
#pragma unroll
        for (int off = 1; off < 16; off <<= 1) {
            p0 += __shfl_xor(p0, off);
            p1 += __shfl_xor(p1, off);
            p2 += __shfl_xor(p2, off);
            p3 += __shfl_xor(p3, off);
        }
        if (llo == 0) {
            int e = e_base + lhi * 4;
            out[e + 0] = p0 + b2;
            out[e + 1] = p1 + b2;
            out[e + 2] = p2 + b2;
            out[e + 3] = p3 + b2;
        }
    }
}

extern "C" void kernel_launch(void* const* d_in, const int* in_sizes, int n_in,
                              void* d_out, int out_size, void* d_ws, size_t ws_size,
                              hipStream_t stream) {
    const float* x   = (const float*)d_in[0];
    const int*   ei  = (const int*)d_in[1];
    const int*   eli = (const int*)d_in[2];
    const float* W1  = (const float*)d_in[3];
    const float* b1  = (const float*)d_in[4];
    const float* W2  = (const float*)d_in[5];
    const float* b2  = (const float*)d_in[6];
    const float* Wp1 = (const float*)d_in[7];
    const float* bp1 = (const float*)d_in[8];
    const float* Wp2 = (const float*)d_in[9];
    const float* bp2 = (const float*)d_in[10];
    float* out = (float*)d_out;

    char* w = (char*)d_ws;
    auto alloc = [&](size_t bytes) {
        char* p = w;
        w += (bytes + 255) & ~(size_t)255;
        return p;
    };
    float*          dinv   = (float*)alloc((size_t)NN * 4);
    int*            rowptr = (int*)alloc((size_t)(NN + 1) * 4);
    int*            histM  = (int*)alloc((size_t)NB * MSB * 4);
    unsigned*       tmp    = (unsigned*)alloc((size_t)EE * 4);
    int*            csr    = (int*)alloc((size_t)EE * 4);
    unsigned short* hA     = (unsigned short*)alloc((size_t)NN * 128 * 2);
    unsigned short* hB     = (unsigned short*)alloc((size_t)NN * 128 * 2);
    unsigned short* W1T    = (unsigned short*)alloc((size_t)128 * 128 * 2);
    unsigned short* W2T    = (unsigned short*)alloc((size_t)128 * 128 * 2);
    unsigned short* WpT    = (unsigned short*)alloc((size_t)128 * 256 * 2);

    const int* srcv = ei;       // row 0
    const int* dstv = ei + EE;  // row 1

    // weight pre-transpose (bf16 [n][k])
    convw_kernel<<<32, 256, 0, stream>>>(W1, W2, Wp1, W1T, W2T, WpT);

    // CSR build: multisplit by dst bucket, then per-bucket local CSR (+rowptr,+dinv)
    ms_hist_kernel<<<MSB, 256, 0, stream>>>(dstv, histM);
    ms_scan_kernel<<<1, 256, 0, stream>>>(histM, rowptr);
    ms_scatter_kernel<<<MSB, 256, 0, stream>>>(srcv, dstv, histM, tmp);
    bucket_csr_kernel<<<NB, 256, 0, stream>>>(tmp, histM, rowptr, dinv, csr);

    int nchunks = (NN + 63) / 64;  // 1563
    // layer 1: hA = bf16(x @ W1); hB = bf16(relu(agg(hA) + b1))
    gemm_mfma_kernel<true><<<1024, 256, 0, stream>>>(x, W1T, hA, NN, nchunks);
    agg_bf16_kernel<<<NN / 4, 256, 0, stream>>>(hA, rowptr, csr, dinv, b1, hB, 1);
    // layer 2: hA = bf16(hB @ W2); hB = bf16(agg(hA) + b2)
    gemm_mfma_kernel<false><<<1024, 256, 0, stream>>>(hB, W2T, hA, NN, nchunks);
    agg_bf16_kernel<<<NN / 4, 256, 0, stream>>>(hA, rowptr, csr, dinv, b2, hB, 0);
    // link scoring
    link_mfma_kernel<<<512, 512, 0, stream>>>(hB, eli, WpT, bp1, Wp2, bp2, out);
}